// Round 1
// baseline (745.255 us; speedup 1.0000x reference)
//
#include <hip/hip_runtime.h>
#include <math.h>

#define N_NODES 100000
#define N_EDGES 3200000
#define N_TOT   (N_EDGES + N_NODES)
#define F_IN    512
#define HID     16
#define NCLS    32
#define NEG_SLOPE 0.2f

#define SCAN_CHUNK 1024
#define SCAN_NB    98   // ceil(100000/1024)

// ---------- edge dtype detection (int64 vs int32) ----------
__global__ __launch_bounds__(64) void k_detect(const int* __restrict__ ei,
                                               int* __restrict__ flag) {
  // If edge_index is int64, every odd int32 word (high half) of the first 64
  // entries is 0. If int32, these are random src ids (P(all zero) ~ 1e-320).
  int v = ei[2 * threadIdx.x + 1];
  unsigned long long m = __ballot(v != 0);
  if (threadIdx.x == 0) *flag = (m == 0ull) ? 1 : 0;  // 1 => int64 layout
}

// ---------- CSR build ----------
__global__ __launch_bounds__(256) void k_count(const int* __restrict__ ei,
                                               const int* __restrict__ flag,
                                               int* __restrict__ cnt) {
  int e = blockIdx.x * 256 + threadIdx.x;
  if (e >= N_EDGES) return;
  int d = (*flag) ? ei[2 * (N_EDGES + e)] : ei[N_EDGES + e];
  atomicAdd(&cnt[d], 1);
}

__global__ __launch_bounds__(256) void k_scan_partial(const int* __restrict__ cnt,
                                                      int* __restrict__ bsum) {
  __shared__ int sm[256];
  int base = blockIdx.x * SCAN_CHUNK;
  int t = threadIdx.x;
  int s = 0;
  for (int j = 0; j < 4; ++j) {
    int i = base + t * 4 + j;
    if (i < N_NODES) s += cnt[i] + 1;   // +1 self loop
  }
  sm[t] = s;
  __syncthreads();
  for (int off = 128; off > 0; off >>= 1) {
    if (t < off) sm[t] += sm[t + off];
    __syncthreads();
  }
  if (t == 0) bsum[blockIdx.x] = sm[0];
}

__global__ __launch_bounds__(128) void k_scan_bsums(int* __restrict__ bsum) {
  __shared__ int sm[128];
  int t = threadIdx.x;
  int orig = (t < SCAN_NB) ? bsum[t] : 0;
  sm[t] = orig;
  __syncthreads();
  for (int off = 1; off < 128; off <<= 1) {
    int v = (t >= off) ? sm[t - off] : 0;
    __syncthreads();
    sm[t] += v;
    __syncthreads();
  }
  if (t < SCAN_NB) bsum[t] = sm[t] - orig;  // exclusive
}

__global__ __launch_bounds__(256) void k_scan_final(const int* __restrict__ cnt,
                                                    const int* __restrict__ bsum,
                                                    int* __restrict__ offs,
                                                    int* __restrict__ pos) {
  __shared__ int sm[256];
  int base = blockIdx.x * SCAN_CHUNK;
  int t = threadIdx.x;
  int v[4];
  int s = 0;
  for (int j = 0; j < 4; ++j) {
    int i = base + t * 4 + j;
    v[j] = (i < N_NODES) ? cnt[i] + 1 : 0;
    s += v[j];
  }
  int orig = s;
  sm[t] = s;
  __syncthreads();
  for (int off = 1; off < 256; off <<= 1) {
    int x = (t >= off) ? sm[t - off] : 0;
    __syncthreads();
    sm[t] += x;
    __syncthreads();
  }
  int run = bsum[blockIdx.x] + (sm[t] - orig);
  for (int j = 0; j < 4; ++j) {
    int i = base + t * 4 + j;
    if (i < N_NODES) {
      offs[i] = run;
      pos[i] = run;
      run += v[j];
    }
  }
  if (blockIdx.x == 0 && t == 0) offs[N_NODES] = N_TOT;
}

__global__ __launch_bounds__(256) void k_fill(const int* __restrict__ ei,
                                              const int* __restrict__ flag,
                                              int* __restrict__ pos,
                                              int* __restrict__ srcS) {
  int e = blockIdx.x * 256 + threadIdx.x;
  if (e >= N_TOT) return;
  int s, d;
  if (e < N_EDGES) {
    if (*flag) { s = ei[2 * e]; d = ei[2 * (N_EDGES + e)]; }
    else       { s = ei[e];     d = ei[N_EDGES + e]; }
  } else {
    s = d = e - N_EDGES;   // self loop
  }
  int p = atomicAdd(&pos[d], 1);
  srcS[p] = s;
}

// ---------- layer GEMMs (thread-per-row; W uniform -> s_load path) ----------
__global__ __launch_bounds__(256) void k_gemm1(const float* __restrict__ x,
                                               const float* __restrict__ W,
                                               const float* __restrict__ atts,
                                               const float* __restrict__ attd,
                                               float* __restrict__ h,
                                               float* __restrict__ as_,
                                               float* __restrict__ ad_) {
  int row = blockIdx.x * 256 + threadIdx.x;
  if (row >= N_NODES) return;
  const float4* xr = (const float4*)(x + (size_t)row * F_IN);
  float acc[HID];
#pragma unroll
  for (int f = 0; f < HID; ++f) acc[f] = 0.f;
  for (int k4 = 0; k4 < F_IN / 4; ++k4) {
    float4 xv = xr[k4];
    const float* Wr = W + k4 * 4 * HID;
#pragma unroll
    for (int f = 0; f < HID; ++f)
      acc[f] += xv.x * Wr[f] + xv.y * Wr[HID + f] +
                xv.z * Wr[2 * HID + f] + xv.w * Wr[3 * HID + f];
  }
  float as = 0.f, ad = 0.f;
#pragma unroll
  for (int f = 0; f < HID; ++f) { as += acc[f] * atts[f]; ad += acc[f] * attd[f]; }
  float4* hp = (float4*)(h + (size_t)row * HID);
  hp[0] = make_float4(acc[0], acc[1], acc[2], acc[3]);
  hp[1] = make_float4(acc[4], acc[5], acc[6], acc[7]);
  hp[2] = make_float4(acc[8], acc[9], acc[10], acc[11]);
  hp[3] = make_float4(acc[12], acc[13], acc[14], acc[15]);
  as_[row] = as;
  ad_[row] = ad;
}

__global__ __launch_bounds__(256) void k_gemm2(const float* __restrict__ hin,
                                               const float* __restrict__ W,
                                               const float* __restrict__ atts,
                                               const float* __restrict__ attd,
                                               float* __restrict__ h2,
                                               float* __restrict__ as_,
                                               float* __restrict__ ad_) {
  int row = blockIdx.x * 256 + threadIdx.x;
  if (row >= N_NODES) return;
  float hv[HID];
  const float4* hp = (const float4*)(hin + (size_t)row * HID);
#pragma unroll
  for (int j = 0; j < 4; ++j) {
    float4 v = hp[j];
    hv[4 * j] = v.x; hv[4 * j + 1] = v.y; hv[4 * j + 2] = v.z; hv[4 * j + 3] = v.w;
  }
  float acc[NCLS];
#pragma unroll
  for (int f = 0; f < NCLS; ++f) acc[f] = 0.f;
#pragma unroll
  for (int k = 0; k < HID; ++k) {
    float xv = hv[k];
    const float* Wr = W + k * NCLS;
#pragma unroll
    for (int f = 0; f < NCLS; ++f) acc[f] += xv * Wr[f];
  }
  float as = 0.f, ad = 0.f;
#pragma unroll
  for (int f = 0; f < NCLS; ++f) { as += acc[f] * atts[f]; ad += acc[f] * attd[f]; }
  float4* op = (float4*)(h2 + (size_t)row * NCLS);
#pragma unroll
  for (int j = 0; j < 8; ++j)
    op[j] = make_float4(acc[4 * j], acc[4 * j + 1], acc[4 * j + 2], acc[4 * j + 3]);
  as_[row] = as;
  ad_[row] = ad;
}

// ---------- per-node softmax + aggregation (wave per node, no atomics) ----------
template <int D, bool FINAL>
__global__ __launch_bounds__(256) void k_aggregate(const int* __restrict__ offs,
                                                   const int* __restrict__ srcS,
                                                   const float* __restrict__ as_,
                                                   const float* __restrict__ ad_,
                                                   const float* __restrict__ h,
                                                   const float* __restrict__ bias,
                                                   float* __restrict__ out) {
  int node = blockIdx.x * 4 + (threadIdx.x >> 6);
  if (node >= N_NODES) return;
  int lane = threadIdx.x & 63;
  int beg = offs[node];
  int end = offs[node + 1];
  float ad = ad_[node];

  // pass 1: online softmax stats over incoming edges (lane-parallel over edges)
  float m = -1e30f, s = 0.f;
  for (int i = beg + lane; i < end; i += 64) {
    int sn = srcS[i];
    float e = as_[sn] + ad;
    e = e > 0.f ? e : NEG_SLOPE * e;
    float nm = fmaxf(m, e);
    s = s * __expf(m - nm) + __expf(e - nm);
    m = nm;
  }
#pragma unroll
  for (int off = 1; off < 64; off <<= 1) {
    float m2 = __shfl_xor(m, off);
    float s2 = __shfl_xor(s, off);
    float nm = fmaxf(m, m2);
    s = s * __expf(m - nm) + s2 * __expf(m2 - nm);
    m = nm;
  }
  float inv_s = 1.f / s;

  // pass 2: weighted gather-sum, feature-parallel (G edge groups x D features)
  constexpr int G = 64 / D;
  int g = lane / D;
  int f = lane % D;
  float acc = 0.f;
  for (int i = beg + g; i < end; i += G) {
    int sn = srcS[i];
    float e = as_[sn] + ad;
    e = e > 0.f ? e : NEG_SLOPE * e;
    float alpha = __expf(e - m) * inv_s;
    acc += alpha * h[(size_t)sn * D + f];
  }
#pragma unroll
  for (int off = D; off < 64; off <<= 1) acc += __shfl_xor(acc, off);

  float val = acc + bias[f];
  if (!FINAL) {
    if (g == 0) out[(size_t)node * D + f] = fmaxf(val, 0.f);  // relu
  } else {
    // log_softmax across the 32 classes held by lanes 0..31 (mirrored 32..63)
    float mx = val;
#pragma unroll
    for (int off = 1; off < 32; off <<= 1) mx = fmaxf(mx, __shfl_xor(mx, off));
    float ex = __expf(val - mx);
    float se = ex;
#pragma unroll
    for (int off = 1; off < 32; off <<= 1) se += __shfl_xor(se, off);
    if (g == 0) out[(size_t)node * D + f] = val - mx - __logf(se);
  }
}

extern "C" void kernel_launch(void* const* d_in, const int* in_sizes, int n_in,
                              void* d_out, int out_size, void* d_ws, size_t ws_size,
                              hipStream_t stream) {
  const float* x    = (const float*)d_in[0];
  const int*   ei   = (const int*)d_in[1];
  const float* W1   = (const float*)d_in[2];
  const float* as1w = (const float*)d_in[3];
  const float* ad1w = (const float*)d_in[4];
  const float* b1   = (const float*)d_in[5];
  const float* W2   = (const float*)d_in[6];
  const float* as2w = (const float*)d_in[7];
  const float* ad2w = (const float*)d_in[8];
  const float* b2   = (const float*)d_in[9];
  float* out = (float*)d_out;

  char* w = (char*)d_ws;
  size_t off = 0;
  auto alloc = [&](size_t bytes) -> char* {
    char* p = w + off;
    off += (bytes + 511) & ~(size_t)511;
    return p;
  };
  int*   flag = (int*)alloc(4);
  int*   cnt  = (int*)alloc((size_t)N_NODES * 4);
  int*   offs = (int*)alloc((size_t)(N_NODES + 1) * 4);
  int*   pos  = (int*)alloc((size_t)N_NODES * 4);
  int*   bsum = (int*)alloc((size_t)SCAN_NB * 4);
  int*   srcS = (int*)alloc((size_t)N_TOT * 4);
  float* h1   = (float*)alloc((size_t)N_NODES * HID * 4);
  float* as1  = (float*)alloc((size_t)N_NODES * 4);
  float* ad1  = (float*)alloc((size_t)N_NODES * 4);
  float* hr   = (float*)alloc((size_t)N_NODES * HID * 4);
  float* h2   = (float*)alloc((size_t)N_NODES * NCLS * 4);
  float* as2  = (float*)alloc((size_t)N_NODES * 4);
  float* ad2  = (float*)alloc((size_t)N_NODES * 4);

  hipMemsetAsync(cnt, 0, (size_t)N_NODES * 4, stream);
  k_detect<<<1, 64, 0, stream>>>(ei, flag);
  k_count<<<(N_EDGES + 255) / 256, 256, 0, stream>>>(ei, flag, cnt);
  k_scan_partial<<<SCAN_NB, 256, 0, stream>>>(cnt, bsum);
  k_scan_bsums<<<1, 128, 0, stream>>>(bsum);
  k_scan_final<<<SCAN_NB, 256, 0, stream>>>(cnt, bsum, offs, pos);
  k_fill<<<(N_TOT + 255) / 256, 256, 0, stream>>>(ei, flag, pos, srcS);
  k_gemm1<<<(N_NODES + 255) / 256, 256, 0, stream>>>(x, W1, as1w, ad1w, h1, as1, ad1);
  k_aggregate<HID, false><<<N_NODES / 4, 256, 0, stream>>>(offs, srcS, as1, ad1, h1, b1, hr);
  k_gemm2<<<(N_NODES + 255) / 256, 256, 0, stream>>>(hr, W2, as2w, ad2w, h2, as2, ad2);
  k_aggregate<NCLS, true><<<N_NODES / 4, 256, 0, stream>>>(offs, srcS, as2, ad2, h2, b2, out);
}